// Round 4
// baseline (625.302 us; speedup 1.0000x reference)
//
#include <hip/hip_runtime.h>
#include <hip/hip_bf16.h>
#include <hip/hip_fp16.h>

typedef float f32x4 __attribute__((ext_vector_type(4)));
typedef short short8 __attribute__((ext_vector_type(8)));
typedef unsigned short u16;
typedef unsigned int u32;

#define LDK 40  // padded LDS k-stride (u16): 80B rows

__device__ __forceinline__ u16 bf16_rne(float x) {
  u32 u = __float_as_uint(x);
  u += 0x7FFFu + ((u >> 16) & 1u);
  return (u16)(u >> 16);
}
__device__ __forceinline__ u32 pack2(float a, float b) {
  return (u32)bf16_rne(a) | ((u32)bf16_rne(b) << 16);
}

// XCD-aware block remap: each XCD gets a contiguous chunk of tile space,
// within it m-tiles grouped by 4 so {4 A-panels + streaming B-panel} fit L2.
// Requires total blocks % 8 == 0 and gy % 4 == 0.
__device__ __forceinline__ void swizzle_xcd(int gx, int gy, int& n, int& m, int& b) {
  int lin = blockIdx.x + gx * (blockIdx.y + gy * blockIdx.z);
  int total = gx * gy * (int)gridDim.z;
  int chunk = total >> 3;
  int nid = (lin & 7) * chunk + (lin >> 3);
  int per_b = gx * gy;
  b = nid / per_b;
  int r = nid - b * per_b;
  int grp = r / (gx * 4);
  int q = r - grp * (gx * 4);
  m = grp * 4 + (q & 3);
  n = q >> 2;
}

// ---------------------------------------------------------------------------
// convert weights only: fp32 -> bf16 RNE. 2048 elems/block, 512 blocks/weight.
// ---------------------------------------------------------------------------
__global__ __launch_bounds__(256)
void convertw_kernel(const float* __restrict__ wq, const float* __restrict__ wk,
                     const float* __restrict__ wv,
                     u16* __restrict__ wqb, u16* __restrict__ wkb,
                     u16* __restrict__ wvb)
{
  int blk = blockIdx.x;
  const float* src; u16* dst; size_t off;
  if (blk < 512)       { src = wq; dst = wqb; off = (size_t)blk * 2048; }
  else if (blk < 1024) { src = wk; dst = wkb; off = (size_t)(blk - 512) * 2048; }
  else                 { src = wv; dst = wvb; off = (size_t)(blk - 1024) * 2048; }
  size_t e = off + (size_t)threadIdx.x * 8;
  float4 a = *(const float4*)(src + e);
  float4 b = *(const float4*)(src + e + 4);
  uint4 o;
  o.x = pack2(a.x, a.y); o.y = pack2(a.z, a.w);
  o.z = pack2(b.x, b.y); o.w = pack2(b.z, b.w);
  *(uint4*)(dst + e) = o;
}

// ---------------------------------------------------------------------------
// staging: 128x32 tile -> LDS (padded LDK)
// ---------------------------------------------------------------------------
__device__ __forceinline__ void stage_tile(const u16* __restrict__ G, int ld,
                                           int kt, u16* L, int tid) {
#pragma unroll
  for (int it = 0; it < 2; ++it) {
    int s = tid + 256 * it;
    int r = s >> 2, c = s & 3;
    *(uint4*)&L[r * LDK + c * 8] = *(const uint4*)(G + (size_t)r * ld + kt + c * 8);
  }
}

// fp32 source, convert to bf16 RNE while staging
__device__ __forceinline__ void stage_tile_f32(const float* __restrict__ G, int ld,
                                               int kt, u16* L, int tid) {
#pragma unroll
  for (int it = 0; it < 2; ++it) {
    int s = tid + 256 * it;
    int r = s >> 2, c = s & 3;
    const float* src = G + (size_t)r * ld + kt + c * 8;
    float4 a = *(const float4*)src;
    float4 b = *(const float4*)(src + 4);
    uint4 o;
    o.x = pack2(a.x, a.y); o.y = pack2(a.z, a.w);
    o.z = pack2(b.x, b.y); o.w = pack2(b.z, b.w);
    *(uint4*)&L[r * LDK + c * 8] = o;
  }
}

#define GEMM_FRAGS_AND_MFMA(Ah, Bh)                                            \
  short8 a_f[4], b_f[4];                                                       \
  _Pragma("unroll")                                                            \
  for (int i = 0; i < 4; ++i) {                                                \
    a_f[i] = *(const short8*)&Ah[(wm + i * 16 + lrow) * LDK + quad * 8];       \
    b_f[i] = *(const short8*)&Bh[(wn + i * 16 + lrow) * LDK + quad * 8];       \
  }                                                                            \
  _Pragma("unroll")                                                            \
  for (int i = 0; i < 4; ++i)                                                  \
    _Pragma("unroll")                                                          \
    for (int j = 0; j < 4; ++j)                                                \
      acc[i][j] = __builtin_amdgcn_mfma_f32_16x16x32_bf16(a_f[i], b_f[j], acc[i][j], 0, 0, 0);

#define GEMM_PROLOGUE                                                          \
  const int tid = threadIdx.x;                                                 \
  const int w = tid >> 6, lane = tid & 63;                                     \
  const int wm = (w >> 1) * 64, wn = (w & 1) * 64;                             \
  const int lrow = lane & 15, quad = lane >> 4;                                \
  f32x4 acc[4][4];                                                             \
  _Pragma("unroll")                                                            \
  for (int i = 0; i < 4; ++i)                                                  \
    _Pragma("unroll")                                                          \
    for (int j = 0; j < 4; ++j) {                                              \
      f32x4 z = {0.f, 0.f, 0.f, 0.f};                                          \
      acc[i][j] = z;                                                           \
    }

// ---------------------------------------------------------------------------
// projq: Y[M,1024] bf16 = A_f32[M,1024] @ Wb[1024,1024]^T + bias   (q and k)
// ---------------------------------------------------------------------------
__global__ __launch_bounds__(256)
void projq_kernel(const float* __restrict__ A, const u16* __restrict__ W,
                  const float* __restrict__ bias, u16* __restrict__ Y)
{
  __shared__ __align__(16) u16 Ah[128 * LDK];
  __shared__ __align__(16) u16 Bh[128 * LDK];
  int nt, mt, bz;
  swizzle_xcd(gridDim.x, gridDim.y, nt, mt, bz);
  const int m0 = mt * 128, n0 = nt * 128;
  GEMM_PROLOGUE
  const float* A_b = A + (size_t)m0 * 1024;
  const u16* B_b = W + (size_t)n0 * 1024;

  for (int kt = 0; kt < 1024; kt += 32) {
    __syncthreads();
    stage_tile_f32(A_b, 1024, kt, Ah, tid);
    stage_tile(B_b, 1024, kt, Bh, tid);
    __syncthreads();
    GEMM_FRAGS_AND_MFMA(Ah, Bh)
  }

#pragma unroll
  for (int j = 0; j < 4; ++j) {
    int gn = n0 + wn + j * 16 + lrow;
    float bj = bias[gn];
#pragma unroll
    for (int i = 0; i < 4; ++i) {
      int gm_base = m0 + wm + i * 16 + quad * 4;
#pragma unroll
      for (int r = 0; r < 4; ++r)
        Y[(size_t)(gm_base + r) * 1024 + gn] = bf16_rne(acc[i][j][r] + bj);
    }
  }
}

// ---------------------------------------------------------------------------
// projv: Vt[b][e][t] bf16 = (ctx @ Wv^T + bv) transposed, via LDS bounce.
// ---------------------------------------------------------------------------
__global__ __launch_bounds__(256)
void projv_kernel(const float* __restrict__ A, const u16* __restrict__ W,
                  const float* __restrict__ bias, u16* __restrict__ Vt)
{
  __shared__ __align__(16) u16 smem[128 * 136];  // 34816 B
  u16* Ah = smem;
  u16* Bh = smem + 128 * LDK;
  int nt, mt, bz;
  swizzle_xcd(gridDim.x, gridDim.y, nt, mt, bz);
  const int m0 = mt * 128, n0 = nt * 128;
  const int bb = m0 >> 11, t0 = m0 & 2047;
  GEMM_PROLOGUE
  const float* A_b = A + (size_t)m0 * 1024;
  const u16* B_b = W + (size_t)n0 * 1024;

  for (int kt = 0; kt < 1024; kt += 32) {
    __syncthreads();
    stage_tile_f32(A_b, 1024, kt, Ah, tid);
    stage_tile(B_b, 1024, kt, Bh, tid);
    __syncthreads();
    GEMM_FRAGS_AND_MFMA(Ah, Bh)
  }

  // transpose via LDS: T[e_local][t_local], stride 136 u16
  __syncthreads();
  u16* T = smem;
#pragma unroll
  for (int j = 0; j < 4; ++j) {
    int e_l = wn + j * 16 + lrow;
    float bj = bias[n0 + e_l];
#pragma unroll
    for (int i = 0; i < 4; ++i) {
      int t_l = wm + i * 16 + quad * 4;
      uint2 p;
      p.x = pack2(acc[i][j][0] + bj, acc[i][j][1] + bj);
      p.y = pack2(acc[i][j][2] + bj, acc[i][j][3] + bj);
      *(uint2*)&T[e_l * 136 + t_l] = p;
    }
  }
  __syncthreads();

  int e_l = tid >> 1, half = tid & 1;
  u16* gdst = Vt + ((size_t)(bb * 1024 + n0 + e_l)) * 2048 + t0 + half * 64;
  const u16* Trow = &T[e_l * 136 + half * 64];
#pragma unroll
  for (int k = 0; k < 8; ++k)
    *(uint4*)(gdst + k * 8) = *(const uint4*)(Trow + k * 8);
}

// ---------------------------------------------------------------------------
// score: S[b,s,t] fp16 = scale * (q[b] @ k[b]^T)
// ---------------------------------------------------------------------------
__global__ __launch_bounds__(256)
void score_kernel(const u16* __restrict__ qb, const u16* __restrict__ kb,
                  _Float16* __restrict__ S)
{
  __shared__ __align__(16) u16 Ah[128 * LDK];
  __shared__ __align__(16) u16 Bh[128 * LDK];
  int nt, mt, b;
  swizzle_xcd(gridDim.x, gridDim.y, nt, mt, b);
  const int m0 = mt * 128, n0 = nt * 128;
  GEMM_PROLOGUE
  const u16* A_b = qb + ((size_t)b * 2048 + m0) * 1024;
  const u16* B_b = kb + ((size_t)b * 2048 + n0) * 1024;

  for (int kt = 0; kt < 1024; kt += 32) {
    __syncthreads();
    stage_tile(A_b, 1024, kt, Ah, tid);
    stage_tile(B_b, 1024, kt, Bh, tid);
    __syncthreads();
    GEMM_FRAGS_AND_MFMA(Ah, Bh)
  }

  const float scale = 0.03125f;  // 1/sqrt(1024)
#pragma unroll
  for (int j = 0; j < 4; ++j) {
    int gn = n0 + wn + j * 16 + lrow;
#pragma unroll
    for (int i = 0; i < 4; ++i) {
      int gm_base = m0 + wm + i * 16 + quad * 4;
#pragma unroll
      for (int r = 0; r < 4; ++r)
        S[((size_t)b * 2048 + gm_base + r) * 2048 + gn] = (_Float16)(acc[i][j][r] * scale);
    }
  }
}

// ---------------------------------------------------------------------------
// softmax over S rows (fp16 in), writes P bf16 in place (same 4096B row).
// One uint4 (8 fp16) per thread.
// ---------------------------------------------------------------------------
__global__ __launch_bounds__(256)
void softmax_kernel(_Float16* __restrict__ S)
{
  const int row = blockIdx.x;
  const int tid = threadIdx.x;
  _Float16* Sr = S + (size_t)row * 2048;
  typedef _Float16 h8 __attribute__((ext_vector_type(8)));
  h8 v = *(const h8*)(Sr + tid * 8);
  float f[8];
#pragma unroll
  for (int i = 0; i < 8; ++i) f[i] = (float)v[i];

  float m = f[0];
#pragma unroll
  for (int i = 1; i < 8; ++i) m = fmaxf(m, f[i]);
#pragma unroll
  for (int off = 32; off > 0; off >>= 1) m = fmaxf(m, __shfl_xor(m, off));

  __shared__ float red[4];
  const int wid = tid >> 6, lane = tid & 63;
  if (lane == 0) red[wid] = m;
  __syncthreads();
  m = fmaxf(fmaxf(red[0], red[1]), fmaxf(red[2], red[3]));

  float e[8], s = 0.f;
#pragma unroll
  for (int i = 0; i < 8; ++i) { e[i] = __expf(f[i] - m); s += e[i]; }
#pragma unroll
  for (int off = 32; off > 0; off >>= 1) s += __shfl_xor(s, off);
  __syncthreads();
  if (lane == 0) red[wid] = s;
  __syncthreads();
  s = red[0] + red[1] + red[2] + red[3];
  float inv = 1.0f / s;

  u16* P = (u16*)S;
  uint4 o;
  o.x = pack2(e[0] * inv, e[1] * inv);
  o.y = pack2(e[2] * inv, e[3] * inv);
  o.z = pack2(e[4] * inv, e[5] * inv);
  o.w = pack2(e[6] * inv, e[7] * inv);
  *(uint4*)&P[(size_t)row * 2048 + tid * 8] = o;
}

// ---------------------------------------------------------------------------
// pv: O[b,s,e] fp32 = P[b] @ Vt[b]^T   (both row stride 2048 u16)
// ---------------------------------------------------------------------------
__global__ __launch_bounds__(256)
void pv_kernel(const u16* __restrict__ P, const u16* __restrict__ Vt,
               float* __restrict__ O)
{
  __shared__ __align__(16) u16 Ah[128 * LDK];
  __shared__ __align__(16) u16 Bh[128 * LDK];
  int nt, mt, b;
  swizzle_xcd(gridDim.x, gridDim.y, nt, mt, b);
  const int m0 = mt * 128, n0 = nt * 128;
  GEMM_PROLOGUE
  const u16* A_b = P + ((size_t)b * 2048 + m0) * 2048;
  const u16* B_b = Vt + ((size_t)b * 1024 + n0) * 2048;

  for (int kt = 0; kt < 2048; kt += 32) {
    __syncthreads();
    stage_tile(A_b, 2048, kt, Ah, tid);
    stage_tile(B_b, 2048, kt, Bh, tid);
    __syncthreads();
    GEMM_FRAGS_AND_MFMA(Ah, Bh)
  }

#pragma unroll
  for (int j = 0; j < 4; ++j) {
    int gn = n0 + wn + j * 16 + lrow;
#pragma unroll
    for (int i = 0; i < 4; ++i) {
      int gm_base = m0 + wm + i * 16 + quad * 4;
#pragma unroll
      for (int r = 0; r < 4; ++r)
        O[((size_t)b * 2048 + gm_base + r) * 1024 + gn] = acc[i][j][r];
    }
  }
}

// ---------------------------------------------------------------------------
extern "C" void kernel_launch(void* const* d_in, const int* in_sizes, int n_in,
                              void* d_out, int out_size, void* d_ws, size_t ws_size,
                              hipStream_t stream) {
  const float* x   = (const float*)d_in[0];
  const float* ctx = (const float*)d_in[1];
  const float* Wq  = (const float*)d_in[2];
  const float* bq  = (const float*)d_in[3];
  const float* Wk  = (const float*)d_in[4];
  const float* bk  = (const float*)d_in[5];
  const float* Wv  = (const float*)d_in[6];
  const float* bv  = (const float*)d_in[7];
  float* out = (float*)d_out;

  // ws (u16 elems): [qb 16.8M][kb 16.8M][vt 16.8M][wqb 1M][wkb][wvb][S 64MiB]
  const size_t NQ = (size_t)16384 * 1024;   // 16.8M
  const size_t NW = (size_t)1024 * 1024;    // 1M
  const size_t needed = (3 * NQ + 3 * NW) * sizeof(u16)
                      + (size_t)16384 * 2048 * sizeof(_Float16);  // ~166 MiB
  if (ws_size < needed) return;

  u16* qb  = (u16*)d_ws;
  u16* kb  = qb + NQ;
  u16* vt  = kb + NQ;
  u16* wqb = vt + NQ;
  u16* wkb = wqb + NW;
  u16* wvb = wkb + NW;
  _Float16* S = (_Float16*)(wvb + NW);

  dim3 blk(256, 1, 1);
  hipLaunchKernelGGL(convertw_kernel, dim3(1536, 1, 1), blk, 0, stream,
                     Wq, Wk, Wv, wqb, wkb, wvb);
  hipLaunchKernelGGL(projq_kernel, dim3(8, 128, 1), blk, 0, stream, x,   wqb, bq, qb);
  hipLaunchKernelGGL(projq_kernel, dim3(8, 128, 1), blk, 0, stream, ctx, wkb, bk, kb);
  hipLaunchKernelGGL(projv_kernel, dim3(8, 128, 1), blk, 0, stream, ctx, wvb, bv, vt);
  hipLaunchKernelGGL(score_kernel, dim3(16, 16, 8), blk, 0, stream, qb, kb, S);
  hipLaunchKernelGGL(softmax_kernel, dim3(16384, 1, 1), blk, 0, stream, S);
  hipLaunchKernelGGL(pv_kernel, dim3(8, 16, 8), blk, 0, stream, (const u16*)S, vt, out);
}